// Round 1
// baseline (139.992 us; speedup 1.0000x reference)
//
#include <hip/hip_runtime.h>

// WaveletLayer: db2 DWT -> gain -> IDWT -> ReLU, fused 6-tap stencil.
// v2: halo via cross-lane shuffles (1 float4 x-load/thread instead of 3),
// g2 via shfl_down (2 ker loads instead of 3), nontemporal float4 stores.
// Only lanes 0/63 of each wave issue predicated halo loads.

#define NN 4096
#define LL 2049
#define PAIRS4 1024  // output quads per row; one thread per quad

typedef float v4f __attribute__((ext_vector_type(4)));

__global__ __launch_bounds__(256) void wavelet_fused(const float* __restrict__ x,
                                                     const float* __restrict__ ker,
                                                     float* __restrict__ out) {
    const int row  = blockIdx.y;
    const int t    = blockIdx.x * 256 + threadIdx.x;   // 0..1023: output quad index
    const int lane = threadIdx.x & 63;

    // db2 decomposition taps
    const float lo0 = -0.12940952255126037f, lo1 = 0.22414386804185735f,
                lo2 =  0.8365163037378079f,  lo3 = 0.48296291314453416f;
    const float hi0 = -0.48296291314453416f, hi1 = 0.8365163037378079f,
                hi2 = -0.22414386804185735f, hi3 = -0.12940952255126037f;

    const v4f*   x4   = (const v4f*)(x + (size_t)row * NN);
    const float* krow = ker + (size_t)row * LL;

    // own data: exactly one float4 x-load + two scalar ker loads per thread
    const v4f   vc = x4[t];
    const float g0 = krow[2 * t];
    const float g1 = krow[2 * t + 1];

    // wave-edge halo: only lanes 0 and 63 load (predicated, exec-masked)
    float ha = 0.0f, hb = 0.0f, hg = 0.0f;
    if (lane == 0) {
        const v4f vp = x4[(t > 0) ? (t - 1) : 0];
        ha = vp.z; hb = vp.w;                       // e0,e1 for lane 0
    } else if (lane == 63) {
        const v4f vn = x4[(t < PAIRS4 - 1) ? (t + 1) : t];
        ha = vn.x; hb = vn.y;                       // e6,e7 for lane 63
        hg = krow[2 * t + 2];                       // g2 for lane 63 (2t+2 <= 2048, valid)
    }

    // interior halo via cross-lane shuffles (lanes are consecutive t within a wave)
    float e0 = __shfl_up(vc.z, 1);    // prev.z
    float e1 = __shfl_up(vc.w, 1);    // prev.w
    float e6 = __shfl_down(vc.x, 1);  // next.x
    float e7 = __shfl_down(vc.y, 1);  // next.y
    float g2 = __shfl_down(g0, 1);    // g[2t+2] = next lane's g0

    if (lane == 0)  { e0 = ha; e1 = hb; }
    if (lane == 63) { e6 = ha; e7 = hb; g2 = hg; }
    // symmetric-padding boundary overrides (same mapping as verified baseline)
    if (t == 0)          { e0 = vc.y; e1 = vc.x; }  // X(-2)=x[1], X(-1)=x[0]
    if (t == PAIRS4 - 1) { e6 = vc.w; e7 = vc.z; }  // X(4096)=x[4095], X(4097)=x[4094]

    const float e2 = vc.x, e3 = vc.y, e4 = vc.z, e5 = vc.w;

    // analysis: cA[j] = lo3*X(2j-2)+lo2*X(2j-1)+lo1*X(2j)+lo0*X(2j+1)
    const float cA0 = lo3 * e0 + lo2 * e1 + lo1 * e2 + lo0 * e3;
    const float cD0 = hi3 * e0 + hi2 * e1 + hi1 * e2 + hi0 * e3;
    const float cA1 = lo3 * e2 + lo2 * e3 + lo1 * e4 + lo0 * e5;
    const float cD1 = hi3 * e2 + hi2 * e3 + hi1 * e4 + hi0 * e5;
    const float cA2 = lo3 * e4 + lo2 * e5 + lo1 * e6 + lo0 * e7;
    const float cD2 = hi3 * e4 + hi2 * e5 + hi1 * e6 + hi0 * e7;

    const float A0 = g0 * cA0, D0 = g0 * cD0;
    const float A1 = g1 * cA1, D1 = g1 * cD1;
    const float A2 = g2 * cA2, D2 = g2 * cD2;

    // synthesis: y[2m] = lo1*A[m]+lo3*A[m+1]+hi1*D[m]+hi3*D[m+1]
    //            y[2m+1] = lo0*A[m]+lo2*A[m+1]+hi0*D[m]+hi2*D[m+1]
    float y0 = lo1 * A0 + lo3 * A1 + hi1 * D0 + hi3 * D1;
    float y1 = lo0 * A0 + lo2 * A1 + hi0 * D0 + hi2 * D1;
    float y2 = lo1 * A1 + lo3 * A2 + hi1 * D1 + hi3 * D2;
    float y3 = lo0 * A1 + lo2 * A2 + hi0 * D1 + hi2 * D2;

    y0 = fmaxf(y0, 0.0f);
    y1 = fmaxf(y1, 0.0f);
    y2 = fmaxf(y2, 0.0f);
    y3 = fmaxf(y3, 0.0f);

    v4f res;
    res.x = y0; res.y = y1; res.z = y2; res.w = y3;

    // out is never re-read by this kernel: nontemporal store keeps L2/L3
    // capacity for the x/ker input streams.
    v4f* out4 = (v4f*)(out + (size_t)row * NN);
    __builtin_nontemporal_store(res, out4 + t);
}

extern "C" void kernel_launch(void* const* d_in, const int* in_sizes, int n_in,
                              void* d_out, int out_size, void* d_ws, size_t ws_size,
                              hipStream_t stream) {
    const float* x   = (const float*)d_in[0];
    const float* ker = (const float*)d_in[1];
    float* out = (float*)d_out;
    wavelet_fused<<<dim3(PAIRS4 / 256, 4096), dim3(256), 0, stream>>>(x, ker, out);
}